// Round 5
// baseline (712.387 us; speedup 1.0000x reference)
//
#include <hip/hip_runtime.h>
#include <hip/hip_bf16.h>

#define B_ 2
#define N_ 2048
#define E_ 1024
#define H_ 16
#define D_ 64
#define T_ (B_*N_)   // 4096 tokens

using s16x8 = __attribute__((ext_vector_type(8))) short;
using f32x4 = __attribute__((ext_vector_type(4))) float;

static __device__ __forceinline__ short f2bf(float f) {
    __hip_bfloat16 h = __float2bfloat16(f);
    union { __hip_bfloat16 h; short s; } u; u.h = h; return u.s;
}
static __device__ __forceinline__ float bf2f(short s) {
    union { short s; __hip_bfloat16 h; } u; u.s = s;
    return __bfloat162float(u.h);
}

// ---------------------------------------------------------------------------
// split x (fp32) -> xh, xl (bf16 hi/lo)
// ---------------------------------------------------------------------------
__global__ __launch_bounds__(256)
void split_x_k(const float* __restrict__ x, short* __restrict__ xh, short* __restrict__ xl)
{
    const int total = (T_*E_)/4;
    for (int i = blockIdx.x*256 + threadIdx.x; i < total; i += gridDim.x*256) {
        const float4 v = ((const float4*)x)[i];
        short h0 = f2bf(v.x), h1 = f2bf(v.y), h2 = f2bf(v.z), h3 = f2bf(v.w);
        short l0 = f2bf(v.x - bf2f(h0)), l1 = f2bf(v.y - bf2f(h1));
        short l2 = f2bf(v.z - bf2f(h2)), l3 = f2bf(v.w - bf2f(h3));
        short4 hs; hs.x=h0; hs.y=h1; hs.z=h2; hs.w=h3;
        short4 ls; ls.x=l0; ls.y=l1; ls.z=l2; ls.w=l3;
        ((short4*)xh)[i] = hs;
        ((short4*)xl)[i] = ls;
    }
}

// ---------------------------------------------------------------------------
// split + transpose W (fp32 [k][n]) -> WhT (, WlT) bf16 [n][k]
// ---------------------------------------------------------------------------
template<int SPLIT>
__global__ __launch_bounds__(256)
void splitwT_k(const float* __restrict__ W, short* __restrict__ WhT, short* __restrict__ WlT)
{
    __shared__ float Ts[64][65];
    const int t = threadIdx.x;
    const int kb = blockIdx.x*64, nb = blockIdx.y*64;
    const int r = t>>4, c4 = (t&15)*4;
    #pragma unroll
    for (int l = 0; l < 4; ++l) {
        const float4 v = *(const float4*)&W[(size_t)(kb + r + l*16)*E_ + nb + c4];
        Ts[c4+0][r+l*16] = v.x; Ts[c4+1][r+l*16] = v.y;
        Ts[c4+2][r+l*16] = v.z; Ts[c4+3][r+l*16] = v.w;
    }
    __syncthreads();
    #pragma unroll
    for (int l = 0; l < 4; ++l) {
        const int np = r + l*16;
        float v0 = Ts[np][c4+0], v1 = Ts[np][c4+1], v2 = Ts[np][c4+2], v3 = Ts[np][c4+3];
        short4 hs; hs.x=f2bf(v0); hs.y=f2bf(v1); hs.z=f2bf(v2); hs.w=f2bf(v3);
        *(short4*)&WhT[(size_t)(nb + np)*E_ + kb + c4] = hs;
        if (SPLIT) {
            short4 ls;
            ls.x = f2bf(v0 - bf2f(hs.x)); ls.y = f2bf(v1 - bf2f(hs.y));
            ls.z = f2bf(v2 - bf2f(hs.z)); ls.w = f2bf(v3 - bf2f(hs.w));
            *(short4*)&WlT[(size_t)(nb + np)*E_ + kb + c4] = ls;
        }
    }
}

// ---------------------------------------------------------------------------
// MFMA GEMM: C[4096,1024] = sum of NPROD products A_p @ B_p^T, + bias.
// A: [4096][1024] bf16 row-major; B given transposed [n][k] bf16.
// No LDS: fragments loaded directly from global (16B/lane, full-line use).
// Per-wave tile 64x32 (mi=4, ni=2); block = 4 waves = 128x64; grid 512 blocks
// (2 blocks/CU, 8 waves/CU for latency hiding).
// EPI 0: fp32 out [t][e]. EPI 1: split hi/lo bf16 to [b,h,n,d].
// EPI 2: bf16 transposed to [b,h,d,n].
// ---------------------------------------------------------------------------
template<int NPROD, int EPI>
__global__ __launch_bounds__(256)
void gemm_mfma_k(const short* __restrict__ Ah, const short* __restrict__ Al,
                 const short* __restrict__ Bh, const short* __restrict__ Bl,
                 const float* __restrict__ bias, void* __restrict__ out0,
                 void* __restrict__ out1)
{
    const int lane = threadIdx.x & 63, wid = threadIdx.x >> 6;
    const int lr = lane & 15, lg = lane >> 4;
    const int bm = blockIdx.x >> 4, bn = blockIdx.x & 15;   // 32 x 16
    const int gm0 = bm*128 + (wid>>1)*64;
    const int gn0 = bn*64  + (wid&1)*32;

    f32x4 acc[4][2];
    #pragma unroll
    for (int i = 0; i < 4; ++i)
        #pragma unroll
        for (int j = 0; j < 2; ++j)
            acc[i][j] = (f32x4){0.f,0.f,0.f,0.f};

    for (int ks = 0; ks < 32; ++ks) {
        const int kk = ks*32 + lg*8;
        s16x8 a0[4], a1[4], b0[2], b1[2];
        #pragma unroll
        for (int mi = 0; mi < 4; ++mi) {
            a0[mi] = *(const s16x8*)(Ah + (size_t)(gm0 + mi*16 + lr)*E_ + kk);
            if (NPROD == 3) a1[mi] = *(const s16x8*)(Al + (size_t)(gm0 + mi*16 + lr)*E_ + kk);
        }
        #pragma unroll
        for (int ni = 0; ni < 2; ++ni) {
            b0[ni] = *(const s16x8*)(Bh + (size_t)(gn0 + ni*16 + lr)*E_ + kk);
            if (NPROD == 3) b1[ni] = *(const s16x8*)(Bl + (size_t)(gn0 + ni*16 + lr)*E_ + kk);
        }
        #pragma unroll
        for (int mi = 0; mi < 4; ++mi)
            #pragma unroll
            for (int ni = 0; ni < 2; ++ni) {
                acc[mi][ni] = __builtin_amdgcn_mfma_f32_16x16x32_bf16(a0[mi], b0[ni], acc[mi][ni], 0, 0, 0);
                if (NPROD == 3) {
                    acc[mi][ni] = __builtin_amdgcn_mfma_f32_16x16x32_bf16(a0[mi], b1[ni], acc[mi][ni], 0, 0, 0);
                    acc[mi][ni] = __builtin_amdgcn_mfma_f32_16x16x32_bf16(a1[mi], b0[ni], acc[mi][ni], 0, 0, 0);
                }
            }
    }

    #pragma unroll
    for (int mi = 0; mi < 4; ++mi)
        #pragma unroll
        for (int ni = 0; ni < 2; ++ni) {
            const int gn = gn0 + ni*16 + lr;
            const float bv = bias[gn];
            if (EPI == 0) {
                float* out = (float*)out0;
                #pragma unroll
                for (int r = 0; r < 4; ++r) {
                    const int row = gm0 + mi*16 + lg*4 + r;
                    out[(size_t)row*E_ + gn] = acc[mi][ni][r] + bv;
                }
            } else if (EPI == 1) {
                short* oh = (short*)out0; short* ol = (short*)out1;
                const int h = gn >> 6, d = gn & 63;
                #pragma unroll
                for (int r = 0; r < 4; ++r) {
                    const int row = gm0 + mi*16 + lg*4 + r;
                    const int b = row >> 11, n = row & (N_-1);
                    const size_t idx = (((size_t)(b*H_ + h))*N_ + n)*D_ + d;
                    const float v = acc[mi][ni][r] + bv;
                    const short hi = f2bf(v);
                    oh[idx] = hi;
                    ol[idx] = f2bf(v - bf2f(hi));
                }
            } else {
                short* ov = (short*)out0;
                const int h = gn >> 6, d = gn & 63;
                const int row0 = gm0 + mi*16 + lg*4;
                const int b = row0 >> 11, n0 = row0 & (N_-1);
                short4 s4;
                s4.x = f2bf(acc[mi][ni][0] + bv);
                s4.y = f2bf(acc[mi][ni][1] + bv);
                s4.z = f2bf(acc[mi][ni][2] + bv);
                s4.w = f2bf(acc[mi][ni][3] + bv);
                *(short4*)&ov[(((size_t)(b*H_ + h))*D_ + d)*N_ + n0] = s4;
            }
        }
}

// ---------------------------------------------------------------------------
// MFMA flash attention. 4 waves x 16 q-rows = 64 q-rows per block.
// Grid = 32 bh x 32 q-blocks = 1024 blocks -> 4 blocks/CU.
// QK^T in bf16x2 (3 products); softmax fp32; PV in bf16.
// K frags read directly from global [b,h,n,d]; V from pre-transposed [b,h,d,n].
// P redistributed per-wave via LDS (no block barriers; stride 68 shorts ->
// <=2-way bank aliasing on u16 writes, which is free).
// Applies the reference's post-softmax /sqrt(E) = /32.
// ---------------------------------------------------------------------------
__global__ __launch_bounds__(256, 4)
void attn_mfma_k(const short* __restrict__ qh, const short* __restrict__ ql,
                 const short* __restrict__ kh, const short* __restrict__ kl,
                 const short* __restrict__ vT, short* __restrict__ aO)
{
    __shared__ __align__(16) short P[64][68];

    const int i = blockIdx.x;
    const int xcd = i & 7, j = i >> 3;     // j 0..127
    const int bh = xcd*4 + (j >> 5);       // chunked per XCD for K/V L2 reuse
    const int q0 = (j & 31) * 64;

    const int lane = threadIdx.x & 63, wid = threadIdx.x >> 6;
    const int lr = lane & 15, lg = lane >> 4;
    const int wq = wid * 16;

    const short* qhb = qh + (size_t)bh*N_*D_;
    const short* qlb = ql + (size_t)bh*N_*D_;
    const short* khb = kh + (size_t)bh*N_*D_;
    const short* klb = kl + (size_t)bh*N_*D_;
    const short* vb  = vT + (size_t)bh*D_*N_;

    // Q fragments resident in registers (16 rows per wave)
    s16x8 q0f[2], q1f[2];
    #pragma unroll
    for (int kc = 0; kc < 2; ++kc) {
        const size_t off = (size_t)(q0 + wq + lr)*D_ + kc*32 + lg*8;
        q0f[kc] = *(const s16x8*)(qhb + off);
        q1f[kc] = *(const s16x8*)(qlb + off);
    }

    f32x4 o[4];
    float m_run[4], l_run[4];
    #pragma unroll
    for (int ni = 0; ni < 4; ++ni) o[ni] = (f32x4){0.f,0.f,0.f,0.f};
    #pragma unroll
    for (int r = 0; r < 4; ++r) { m_run[r] = -3.0e38f; l_run[r] = 0.f; }

    for (int kv0 = 0; kv0 < N_; kv0 += 64) {
        // ---- S = Q K^T (bf16x2, 3 products) ----
        f32x4 s[4];
        #pragma unroll
        for (int ni = 0; ni < 4; ++ni) s[ni] = (f32x4){0.f,0.f,0.f,0.f};

        #pragma unroll
        for (int kc = 0; kc < 2; ++kc)
            #pragma unroll
            for (int ni = 0; ni < 4; ++ni) {
                const size_t off = (size_t)(kv0 + ni*16 + lr)*D_ + kc*32 + lg*8;
                const s16x8 kh8 = *(const s16x8*)(khb + off);
                const s16x8 kl8 = *(const s16x8*)(klb + off);
                s[ni] = __builtin_amdgcn_mfma_f32_16x16x32_bf16(q0f[kc], kh8, s[ni], 0, 0, 0);
                s[ni] = __builtin_amdgcn_mfma_f32_16x16x32_bf16(q0f[kc], kl8, s[ni], 0, 0, 0);
                s[ni] = __builtin_amdgcn_mfma_f32_16x16x32_bf16(q1f[kc], kh8, s[ni], 0, 0, 0);
            }

        // ---- online softmax (row stats across 16 lanes x 4 ni) ----
        #pragma unroll
        for (int r = 0; r < 4; ++r) {
            float mt = fmaxf(fmaxf(s[0][r], s[1][r]), fmaxf(s[2][r], s[3][r]));
            mt = fmaxf(mt, __shfl_xor(mt, 1));
            mt = fmaxf(mt, __shfl_xor(mt, 2));
            mt = fmaxf(mt, __shfl_xor(mt, 4));
            mt = fmaxf(mt, __shfl_xor(mt, 8));
            const float mnew = fmaxf(m_run[r], mt);
            const float sc   = __expf(m_run[r] - mnew);
            float ps = 0.f;
            #pragma unroll
            for (int ni = 0; ni < 4; ++ni) {
                const float p = __expf(s[ni][r] - mnew);
                s[ni][r] = p;
                ps += p;
            }
            ps += __shfl_xor(ps, 1);
            ps += __shfl_xor(ps, 2);
            ps += __shfl_xor(ps, 4);
            ps += __shfl_xor(ps, 8);
            l_run[r] = l_run[r]*sc + ps;
            m_run[r] = mnew;
            #pragma unroll
            for (int ni = 0; ni < 4; ++ni) o[ni][r] *= sc;
        }

        // ---- P -> LDS (own wave's rows only; no block sync needed) ----
        #pragma unroll
        for (int ni = 0; ni < 4; ++ni)
            #pragma unroll
            for (int r = 0; r < 4; ++r)
                P[wq + lg*4 + r][ni*16 + lr] = f2bf(s[ni][r]);

        // ---- O += P @ V ----
        #pragma unroll
        for (int kc = 0; kc < 2; ++kc) {
            const s16x8 p8 = *(const s16x8*)&P[wq + lr][kc*32 + lg*8];
            #pragma unroll
            for (int ni = 0; ni < 4; ++ni) {
                const s16x8 v8 = *(const s16x8*)(vb + (size_t)(ni*16 + lr)*N_ + kv0 + kc*32 + lg*8);
                o[ni] = __builtin_amdgcn_mfma_f32_16x16x32_bf16(p8, v8, o[ni], 0, 0, 0);
            }
        }
    }

    // ---- epilogue: /l, /32, store bf16 [t][e] for output GEMM ----
    const int b = bh >> 4, h = bh & 15;
    #pragma unroll
    for (int r = 0; r < 4; ++r) {
        const float inv = 1.0f / (l_run[r] * 32.0f);
        const int n = q0 + wq + lg*4 + r;
        #pragma unroll
        for (int ni = 0; ni < 4; ++ni) {
            const int e = h*64 + ni*16 + lr;
            aO[(size_t)(b*N_ + n)*E_ + e] = f2bf(o[ni][r] * inv);
        }
    }
}

// ---------------------------------------------------------------------------
extern "C" void kernel_launch(void* const* d_in, const int* in_sizes, int n_in,
                              void* d_out, int out_size, void* d_ws, size_t ws_size,
                              hipStream_t stream)
{
    const float* x  = (const float*)d_in[0];
    const float* Wq = (const float*)d_in[1];
    const float* bq = (const float*)d_in[2];
    const float* Wk = (const float*)d_in[3];
    const float* bk = (const float*)d_in[4];
    const float* Wv = (const float*)d_in[5];
    const float* bv = (const float*)d_in[6];
    const float* Wo = (const float*)d_in[7];
    const float* bo = (const float*)d_in[8];
    float* out = (float*)d_out;

    const size_t MB = 1024*1024ULL;
    char* ws = (char*)d_ws;
    short* xh  = (short*)(ws + 0*MB);    // 8 MB
    short* xl  = (short*)(ws + 8*MB);    // 8 MB
    short* WhT = (short*)(ws + 16*MB);   // 2 MB
    short* WlT = (short*)(ws + 18*MB);   // 2 MB
    short* vT  = (short*)(ws + 20*MB);   // 8 MB  [b,h,d,n]
    short* qh  = (short*)(ws + 28*MB);   // 8 MB  [b,h,n,d]
    short* ql  = (short*)(ws + 36*MB);
    short* kh  = (short*)(ws + 44*MB);
    short* kl  = (short*)(ws + 52*MB);
    short* aO  = (short*)(ws + 0*MB);    // aliases xh (dead after K-proj)

    dim3 gw(16, 16);

    split_x_k<<<1024, 256, 0, stream>>>(x, xh, xl);

    // V projection (plain bf16), output pre-transposed [b,h,d,n]
    splitwT_k<0><<<gw, 256, 0, stream>>>(Wv, WhT, nullptr);
    gemm_mfma_k<1,2><<<512, 256, 0, stream>>>(xh, nullptr, WhT, nullptr, bv, vT, nullptr);

    // Q projection (bf16x2, 3 products), split outputs
    splitwT_k<1><<<gw, 256, 0, stream>>>(Wq, WhT, WlT);
    gemm_mfma_k<3,1><<<512, 256, 0, stream>>>(xh, xl, WhT, WlT, bq, qh, ql);

    // K projection
    splitwT_k<1><<<gw, 256, 0, stream>>>(Wk, WhT, WlT);
    gemm_mfma_k<3,1><<<512, 256, 0, stream>>>(xh, xl, WhT, WlT, bk, kh, kl);

    // attention
    attn_mfma_k<<<1024, 256, 0, stream>>>(qh, ql, kh, kl, vT, aO);

    // output projection (plain bf16 -> fp32 out)
    splitwT_k<0><<<gw, 256, 0, stream>>>(Wo, WhT, nullptr);
    gemm_mfma_k<1,0><<<512, 256, 0, stream>>>(aO, nullptr, WhT, nullptr, bo, out, nullptr);
}

// Round 7
// 321.778 us; speedup vs baseline: 2.2139x; 2.2139x over previous
//
#include <hip/hip_runtime.h>
#include <hip/hip_bf16.h>

#define B_ 2
#define N_ 2048
#define E_ 1024
#define H_ 16
#define D_ 64
#define T_ (B_*N_)   // 4096 tokens

using s16x8 = __attribute__((ext_vector_type(8))) short;
using f32x4 = __attribute__((ext_vector_type(4))) float;

static __device__ __forceinline__ short f2bf(float f) {
    __hip_bfloat16 h = __float2bfloat16(f);
    union { __hip_bfloat16 h; short s; } u; u.h = h; return u.s;
}
static __device__ __forceinline__ float bf2f(short s) {
    union { short s; __hip_bfloat16 h; } u; u.s = s;
    return __bfloat162float(u.h);
}

// global -> LDS direct copy, 16B per lane (wave-uniform LDS base + lane*16).
typedef const __attribute__((address_space(1))) unsigned int gas_u32;
typedef __attribute__((address_space(3))) unsigned int las_u32;
static __device__ __forceinline__ void gl_lds16(const void* g, void* l) {
    __builtin_amdgcn_global_load_lds((gas_u32*)g, (las_u32*)l, 16, 0, 0);
}

// ---------------------------------------------------------------------------
// split x (fp32) -> xh, xl (bf16 hi/lo)
// ---------------------------------------------------------------------------
__global__ __launch_bounds__(256)
void split_x_k(const float* __restrict__ x, short* __restrict__ xh, short* __restrict__ xl)
{
    const int total = (T_*E_)/4;
    for (int i = blockIdx.x*256 + threadIdx.x; i < total; i += gridDim.x*256) {
        const float4 v = ((const float4*)x)[i];
        short h0 = f2bf(v.x), h1 = f2bf(v.y), h2 = f2bf(v.z), h3 = f2bf(v.w);
        short l0 = f2bf(v.x - bf2f(h0)), l1 = f2bf(v.y - bf2f(h1));
        short l2 = f2bf(v.z - bf2f(h2)), l3 = f2bf(v.w - bf2f(h3));
        short4 hs; hs.x=h0; hs.y=h1; hs.z=h2; hs.w=h3;
        short4 ls; ls.x=l0; ls.y=l1; ls.z=l2; ls.w=l3;
        ((short4*)xh)[i] = hs;
        ((short4*)xl)[i] = ls;
    }
}

// ---------------------------------------------------------------------------
// split + transpose W (fp32 [k][n]) -> WhT (, WlT) bf16 [n][k]
// ---------------------------------------------------------------------------
template<int SPLIT>
__global__ __launch_bounds__(256)
void splitwT_k(const float* __restrict__ W, short* __restrict__ WhT, short* __restrict__ WlT)
{
    __shared__ float Ts[64][65];
    const int t = threadIdx.x;
    const int kb = blockIdx.x*64, nb = blockIdx.y*64;
    const int r = t>>4, c4 = (t&15)*4;
    #pragma unroll
    for (int l = 0; l < 4; ++l) {
        const float4 v = *(const float4*)&W[(size_t)(kb + r + l*16)*E_ + nb + c4];
        Ts[c4+0][r+l*16] = v.x; Ts[c4+1][r+l*16] = v.y;
        Ts[c4+2][r+l*16] = v.z; Ts[c4+3][r+l*16] = v.w;
    }
    __syncthreads();
    #pragma unroll
    for (int l = 0; l < 4; ++l) {
        const int np = r + l*16;
        float v0 = Ts[np][c4+0], v1 = Ts[np][c4+1], v2 = Ts[np][c4+2], v3 = Ts[np][c4+3];
        short4 hs; hs.x=f2bf(v0); hs.y=f2bf(v1); hs.z=f2bf(v2); hs.w=f2bf(v3);
        *(short4*)&WhT[(size_t)(nb + np)*E_ + kb + c4] = hs;
        if (SPLIT) {
            short4 ls;
            ls.x = f2bf(v0 - bf2f(hs.x)); ls.y = f2bf(v1 - bf2f(hs.y));
            ls.z = f2bf(v2 - bf2f(hs.z)); ls.w = f2bf(v3 - bf2f(hs.w));
            *(short4*)&WlT[(size_t)(nb + np)*E_ + kb + c4] = ls;
        }
    }
}

// ---------------------------------------------------------------------------
// LDS-staged MFMA GEMM: C[4096,1024] = sum of NPROD A_p @ B_p^T + bias.
// Block tile 64(M) x 128(N), BK=64, 4 waves (2x2 -> each 32x64, mi2 x ni4).
// Operand tiles staged once per block via global_load_lds(16) with XOR-chunk
// swizzle (chunk ^= row&7 within 128B rows): pre-swizzled global source +
// swizzled LDS read (both-sides rule) -> conflict-free ds_read_b128.
// Grid 512 = 64 M-tiles x 8 N-panels; bn = blockIdx&7 gives per-XCD W reuse.
// EPI 0: fp32 [t][e]. EPI 1: split hi/lo bf16 [b,h,n,d]. EPI 2: bf16 [b,h,d,n].
// ---------------------------------------------------------------------------
template<int NPROD, int EPI>
__global__ __launch_bounds__(256)
void gemm_mfma_k(const short* __restrict__ Ah_g, const short* __restrict__ Al_g,
                 const short* __restrict__ Bh_g, const short* __restrict__ Bl_g,
                 const float* __restrict__ bias, void* __restrict__ out0,
                 void* __restrict__ out1)
{
    __shared__ __align__(16) short Ah[64*64];
    __shared__ __align__(16) short Bh[128*64];
    __shared__ __align__(16) short Al[(NPROD==3)?64*64:8];
    __shared__ __align__(16) short Bl[(NPROD==3)?128*64:8];

    const int lane = threadIdx.x & 63, wid = threadIdx.x >> 6;
    const int lr = lane & 15, lg = lane >> 4;
    const int bm = blockIdx.x >> 3, bn = blockIdx.x & 7;
    const int wm = (wid>>1)*32, wn = (wid&1)*64;       // wave offsets in tile
    const int gm0 = bm*64 + wm;
    const int gn0 = bn*128 + wn;

    const int lrow = lane >> 3;                 // row within 8-row stage instr
    const int lsw8 = (((lane & 7) ^ lrow)) * 8; // pre-swizzled source chunk (elems)

    f32x4 acc[2][4];
    #pragma unroll
    for (int i = 0; i < 2; ++i)
        #pragma unroll
        for (int j = 0; j < 4; ++j)
            acc[i][j] = (f32x4){0.f,0.f,0.f,0.f};

    for (int k0 = 0; k0 < E_; k0 += 64) {
        // ---- stage tiles (all waves participate; 1KB per instr) ----
        if (NPROD == 3) {
            #pragma unroll
            for (int s = 0; s < 12; ++s) {
                const int j = wid + 4*s;        // 0..47
                if (j < 8)
                    gl_lds16(Ah_g + (size_t)(bm*64 + j*8 + lrow)*E_ + k0 + lsw8, &Ah[j*512]);
                else if (j < 16)
                    gl_lds16(Al_g + (size_t)(bm*64 + (j-8)*8 + lrow)*E_ + k0 + lsw8, &Al[(j-8)*512]);
                else if (j < 32)
                    gl_lds16(Bh_g + (size_t)(bn*128 + (j-16)*8 + lrow)*E_ + k0 + lsw8, &Bh[(j-16)*512]);
                else
                    gl_lds16(Bl_g + (size_t)(bn*128 + (j-32)*8 + lrow)*E_ + k0 + lsw8, &Bl[(j-32)*512]);
            }
        } else {
            #pragma unroll
            for (int s = 0; s < 6; ++s) {
                const int j = wid + 4*s;        // 0..23
                if (j < 8)
                    gl_lds16(Ah_g + (size_t)(bm*64 + j*8 + lrow)*E_ + k0 + lsw8, &Ah[j*512]);
                else
                    gl_lds16(Bh_g + (size_t)(bn*128 + (j-8)*8 + lrow)*E_ + k0 + lsw8, &Bh[(j-8)*512]);
            }
        }
        __syncthreads();   // compiler drains vmcnt before s_barrier -> LDS valid

        // ---- compute from LDS ----
        #pragma unroll
        for (int kc = 0; kc < 2; ++kc) {
            s16x8 a0[2], a1[2], b0[4], b1[4];
            #pragma unroll
            for (int mi = 0; mi < 2; ++mi) {
                const int ar = wm + mi*16 + lr;
                const int ao = ar*64 + (((kc*4+lg) ^ (ar&7))<<3);
                a0[mi] = *(const s16x8*)&Ah[ao];
                if (NPROD == 3) a1[mi] = *(const s16x8*)&Al[ao];
            }
            #pragma unroll
            for (int ni = 0; ni < 4; ++ni) {
                const int br = wn + ni*16 + lr;
                const int bo = br*64 + (((kc*4+lg) ^ (br&7))<<3);
                b0[ni] = *(const s16x8*)&Bh[bo];
                if (NPROD == 3) b1[ni] = *(const s16x8*)&Bl[bo];
            }
            #pragma unroll
            for (int mi = 0; mi < 2; ++mi)
                #pragma unroll
                for (int ni = 0; ni < 4; ++ni) {
                    acc[mi][ni] = __builtin_amdgcn_mfma_f32_16x16x32_bf16(a0[mi], b0[ni], acc[mi][ni], 0, 0, 0);
                    if (NPROD == 3) {
                        acc[mi][ni] = __builtin_amdgcn_mfma_f32_16x16x32_bf16(a0[mi], b1[ni], acc[mi][ni], 0, 0, 0);
                        acc[mi][ni] = __builtin_amdgcn_mfma_f32_16x16x32_bf16(a1[mi], b0[ni], acc[mi][ni], 0, 0, 0);
                    }
                }
        }
        __syncthreads();   // reads done before next stage overwrites
    }

    #pragma unroll
    for (int mi = 0; mi < 2; ++mi)
        #pragma unroll
        for (int ni = 0; ni < 4; ++ni) {
            const int gn = gn0 + ni*16 + lr;
            const float bv = bias[gn];
            if (EPI == 0) {
                float* out = (float*)out0;
                #pragma unroll
                for (int r = 0; r < 4; ++r) {
                    const int row = gm0 + mi*16 + lg*4 + r;
                    out[(size_t)row*E_ + gn] = acc[mi][ni][r] + bv;
                }
            } else if (EPI == 1) {
                short* oh = (short*)out0; short* ol = (short*)out1;
                const int h = gn >> 6, d = gn & 63;
                #pragma unroll
                for (int r = 0; r < 4; ++r) {
                    const int row = gm0 + mi*16 + lg*4 + r;
                    const int b = row >> 11, n = row & (N_-1);
                    const size_t idx = (((size_t)(b*H_ + h))*N_ + n)*D_ + d;
                    const float v = acc[mi][ni][r] + bv;
                    const short hi = f2bf(v);
                    oh[idx] = hi;
                    ol[idx] = f2bf(v - bf2f(hi));
                }
            } else {
                short* ov = (short*)out0;
                const int h = gn >> 6, d = gn & 63;
                const int row0 = gm0 + mi*16 + lg*4;
                const int b = row0 >> 11, n0 = row0 & (N_-1);
                short4 s4;
                s4.x = f2bf(acc[mi][ni][0] + bv);
                s4.y = f2bf(acc[mi][ni][1] + bv);
                s4.z = f2bf(acc[mi][ni][2] + bv);
                s4.w = f2bf(acc[mi][ni][3] + bv);
                *(short4*)&ov[(((size_t)(b*H_ + h))*D_ + d)*N_ + n0] = s4;
            }
        }
}

// ---------------------------------------------------------------------------
// LDS-staged MFMA flash attention. 4 waves x 32 q-rows = 128 q-rows/block.
// Grid 512 (32 bh x 16 q-blocks), XCD-chunked bh for K/V L2 reuse.
// Per kv tile of 64: Kh/Kl/V staged ONCE per block (24 gload_lds instrs,
// shared by 4 waves) with the same XOR-chunk swizzle; QK^T bf16x2 (3 MFMA),
// fp32 online softmax, PV bf16. P per-wave in LDS (stride 72 = 16B-aligned).
// Applies the reference's post-softmax /sqrt(E) = /32.
// ---------------------------------------------------------------------------
__global__ __launch_bounds__(256)
void attn_mfma_k(const short* __restrict__ qh, const short* __restrict__ ql,
                 const short* __restrict__ kh, const short* __restrict__ kl,
                 const short* __restrict__ vT, short* __restrict__ aO)
{
    __shared__ __align__(16) short Khs[64*64];
    __shared__ __align__(16) short Kls[64*64];
    __shared__ __align__(16) short Vts[64*64];
    __shared__ __align__(16) short P[128][72];

    const int i = blockIdx.x;
    const int xcd = i & 7, j = i >> 3;     // j 0..63
    const int bh = xcd*4 + (j >> 4);       // 4 bh per XCD
    const int q0 = (j & 15) * 128;

    const int lane = threadIdx.x & 63, wid = threadIdx.x >> 6;
    const int lr = lane & 15, lg = lane >> 4;
    const int wq = wid * 32;

    const short* qhb = qh + (size_t)bh*N_*D_;
    const short* qlb = ql + (size_t)bh*N_*D_;
    const short* khb = kh + (size_t)bh*N_*D_;
    const short* klb = kl + (size_t)bh*N_*D_;
    const short* vb  = vT + (size_t)bh*D_*N_;

    const int lrow = lane >> 3;
    const int lsw8 = (((lane & 7) ^ lrow)) * 8;

    // Q fragments resident in registers (32 rows per wave: mi=2)
    s16x8 q0f[2][2], q1f[2][2];
    #pragma unroll
    for (int mi = 0; mi < 2; ++mi)
        #pragma unroll
        for (int kc = 0; kc < 2; ++kc) {
            const size_t off = (size_t)(q0 + wq + mi*16 + lr)*D_ + kc*32 + lg*8;
            q0f[mi][kc] = *(const s16x8*)(qhb + off);
            q1f[mi][kc] = *(const s16x8*)(qlb + off);
        }

    f32x4 o[2][4];
    float m_run[2][4], l_run[2][4];
    #pragma unroll
    for (int mi = 0; mi < 2; ++mi) {
        #pragma unroll
        for (int ni = 0; ni < 4; ++ni) o[mi][ni] = (f32x4){0.f,0.f,0.f,0.f};
        #pragma unroll
        for (int r = 0; r < 4; ++r) { m_run[mi][r] = -3.0e38f; l_run[mi][r] = 0.f; }
    }

    for (int kv0 = 0; kv0 < N_; kv0 += 64) {
        // ---- stage Kh/Kl/V tiles once per block ----
        #pragma unroll
        for (int s = 0; s < 6; ++s) {
            const int jj = wid + 4*s;          // 0..23
            if (jj < 8)
                gl_lds16(khb + (size_t)(kv0 + jj*8 + lrow)*D_ + lsw8, &Khs[jj*512]);
            else if (jj < 16)
                gl_lds16(klb + (size_t)(kv0 + (jj-8)*8 + lrow)*D_ + lsw8, &Kls[(jj-8)*512]);
            else
                gl_lds16(vb + (size_t)((jj-16)*8 + lrow)*N_ + kv0 + lsw8, &Vts[(jj-16)*512]);
        }
        __syncthreads();

        // ---- S = Q K^T (bf16x2, 3 products) from LDS ----
        f32x4 s[2][4];
        #pragma unroll
        for (int mi = 0; mi < 2; ++mi)
            #pragma unroll
            for (int ni = 0; ni < 4; ++ni) s[mi][ni] = (f32x4){0.f,0.f,0.f,0.f};

        #pragma unroll
        for (int kc = 0; kc < 2; ++kc)
            #pragma unroll
            for (int ni = 0; ni < 4; ++ni) {
                const int kr = ni*16 + lr;
                const int ko = kr*64 + (((kc*4+lg) ^ (kr&7))<<3);
                const s16x8 kh8 = *(const s16x8*)&Khs[ko];
                const s16x8 kl8 = *(const s16x8*)&Kls[ko];
                #pragma unroll
                for (int mi = 0; mi < 2; ++mi) {
                    s[mi][ni] = __builtin_amdgcn_mfma_f32_16x16x32_bf16(q0f[mi][kc], kh8, s[mi][ni], 0, 0, 0);
                    s[mi][ni] = __builtin_amdgcn_mfma_f32_16x16x32_bf16(q0f[mi][kc], kl8, s[mi][ni], 0, 0, 0);
                    s[mi][ni] = __builtin_amdgcn_mfma_f32_16x16x32_bf16(q1f[mi][kc], kh8, s[mi][ni], 0, 0, 0);
                }
            }

        // ---- online softmax (row stats across 16 lanes x 4 ni) ----
        #pragma unroll
        for (int mi = 0; mi < 2; ++mi)
            #pragma unroll
            for (int r = 0; r < 4; ++r) {
                float mt = fmaxf(fmaxf(s[mi][0][r], s[mi][1][r]),
                                 fmaxf(s[mi][2][r], s[mi][3][r]));
                mt = fmaxf(mt, __shfl_xor(mt, 1));
                mt = fmaxf(mt, __shfl_xor(mt, 2));
                mt = fmaxf(mt, __shfl_xor(mt, 4));
                mt = fmaxf(mt, __shfl_xor(mt, 8));
                const float mnew = fmaxf(m_run[mi][r], mt);
                const float sc   = __expf(m_run[mi][r] - mnew);
                float ps = 0.f;
                #pragma unroll
                for (int ni = 0; ni < 4; ++ni) {
                    const float p = __expf(s[mi][ni][r] - mnew);
                    s[mi][ni][r] = p;
                    ps += p;
                }
                ps += __shfl_xor(ps, 1);
                ps += __shfl_xor(ps, 2);
                ps += __shfl_xor(ps, 4);
                ps += __shfl_xor(ps, 8);
                l_run[mi][r] = l_run[mi][r]*sc + ps;
                m_run[mi][r] = mnew;
                #pragma unroll
                for (int ni = 0; ni < 4; ++ni) o[mi][ni][r] *= sc;
            }

        // ---- P -> LDS (own wave's rows; no cross-wave hazard) ----
        #pragma unroll
        for (int mi = 0; mi < 2; ++mi)
            #pragma unroll
            for (int ni = 0; ni < 4; ++ni)
                #pragma unroll
                for (int r = 0; r < 4; ++r)
                    P[wq + mi*16 + lg*4 + r][ni*16 + lr] = f2bf(s[mi][ni][r]);

        // ---- O += P @ V ----
        #pragma unroll
        for (int kc = 0; kc < 2; ++kc) {
            s16x8 p8[2];
            #pragma unroll
            for (int mi = 0; mi < 2; ++mi)
                p8[mi] = *(const s16x8*)&P[wq + mi*16 + lr][kc*32 + lg*8];
            #pragma unroll
            for (int ni = 0; ni < 4; ++ni) {
                const int vr = ni*16 + lr;
                const int vo = vr*64 + (((kc*4+lg) ^ (vr&7))<<3);
                const s16x8 v8 = *(const s16x8*)&Vts[vo];
                #pragma unroll
                for (int mi = 0; mi < 2; ++mi)
                    o[mi][ni] = __builtin_amdgcn_mfma_f32_16x16x32_bf16(p8[mi], v8, o[mi][ni], 0, 0, 0);
            }
        }
        __syncthreads();   // all waves done reading K/V before next stage
    }

    // ---- epilogue: /l, /32, store bf16 [t][e] for output GEMM ----
    const int b = bh >> 4, h = bh & 15;
    #pragma unroll
    for (int mi = 0; mi < 2; ++mi)
        #pragma unroll
        for (int r = 0; r < 4; ++r) {
            const float inv = 1.0f / (l_run[mi][r] * 32.0f);
            const int n = q0 + wq + mi*16 + lg*4 + r;
            #pragma unroll
            for (int ni = 0; ni < 4; ++ni) {
                const int e = h*64 + ni*16 + lr;
                aO[(size_t)(b*N_ + n)*E_ + e] = f2bf(o[mi][ni][r] * inv);
            }
        }
}

// ---------------------------------------------------------------------------
extern "C" void kernel_launch(void* const* d_in, const int* in_sizes, int n_in,
                              void* d_out, int out_size, void* d_ws, size_t ws_size,
                              hipStream_t stream)
{
    const float* x  = (const float*)d_in[0];
    const float* Wq = (const float*)d_in[1];
    const float* bq = (const float*)d_in[2];
    const float* Wk = (const float*)d_in[3];
    const float* bk = (const float*)d_in[4];
    const float* Wv = (const float*)d_in[5];
    const float* bv = (const float*)d_in[6];
    const float* Wo = (const float*)d_in[7];
    const float* bo = (const float*)d_in[8];
    float* out = (float*)d_out;

    const size_t MB = 1024*1024ULL;
    char* ws = (char*)d_ws;
    short* xh  = (short*)(ws + 0*MB);    // 8 MB
    short* xl  = (short*)(ws + 8*MB);    // 8 MB
    short* WhT = (short*)(ws + 16*MB);   // 2 MB
    short* WlT = (short*)(ws + 18*MB);   // 2 MB
    short* vT  = (short*)(ws + 20*MB);   // 8 MB  [b,h,d,n]
    short* qh  = (short*)(ws + 28*MB);   // 8 MB  [b,h,n,d]
    short* ql  = (short*)(ws + 36*MB);
    short* kh  = (short*)(ws + 44*MB);
    short* kl  = (short*)(ws + 52*MB);
    short* aO  = (short*)(ws + 0*MB);    // aliases xh (dead after K-proj)

    dim3 gw(16, 16);

    split_x_k<<<1024, 256, 0, stream>>>(x, xh, xl);

    // V projection (plain bf16), output pre-transposed [b,h,d,n]
    splitwT_k<0><<<gw, 256, 0, stream>>>(Wv, WhT, nullptr);
    gemm_mfma_k<1,2><<<512, 256, 0, stream>>>(xh, nullptr, WhT, nullptr, bv, vT, nullptr);

    // Q projection (bf16x2, 3 products), split outputs
    splitwT_k<1><<<gw, 256, 0, stream>>>(Wq, WhT, WlT);
    gemm_mfma_k<3,1><<<512, 256, 0, stream>>>(xh, xl, WhT, WlT, bq, qh, ql);

    // K projection
    splitwT_k<1><<<gw, 256, 0, stream>>>(Wk, WhT, WlT);
    gemm_mfma_k<3,1><<<512, 256, 0, stream>>>(xh, xl, WhT, WlT, bk, kh, kl);

    // attention
    attn_mfma_k<<<512, 256, 0, stream>>>(qh, ql, kh, kl, vT, aO);

    // output projection (plain bf16 -> fp32 out)
    splitwT_k<0><<<gw, 256, 0, stream>>>(Wo, WhT, nullptr);
    gemm_mfma_k<1,0><<<512, 256, 0, stream>>>(aO, nullptr, WhT, nullptr, bo, out, nullptr);
}